// Round 18
// baseline (200.501 us; speedup 1.0000x reference)
//
#include <hip/hip_runtime.h>
#include <hip/hip_bf16.h>
#include <cstdint>

#define NEGV -1e9f

typedef __attribute__((ext_vector_type(8))) short short8v;  // 8 bf16 = 4 VGPR
typedef __attribute__((ext_vector_type(4))) float f32x4;

union U8 {
  unsigned u[4];
  short8v v;
};

// ---------------- wave helpers (wave64) ----------------
__device__ __forceinline__ float wred_sum(float v) {
#pragma unroll
  for (int o = 32; o; o >>= 1) v += __shfl_xor(v, o);
  return v;
}
__device__ __forceinline__ float wred_max(float v) {
#pragma unroll
  for (int o = 32; o; o >>= 1) v = fmaxf(v, __shfl_xor(v, o));
  return v;
}
template <int CTRL>
__device__ __forceinline__ float dpp_fadd(float x) {
  int xi = __float_as_int(x);
  int yi = __builtin_amdgcn_update_dpp(xi, xi, CTRL, 0xF, 0xF, false);
  return x + __int_as_float(yi);
}
__device__ __forceinline__ float dpp_sum63(float v) {
  v = dpp_fadd<0xB1>(v);
  v = dpp_fadd<0x4E>(v);
  v = dpp_fadd<0x141>(v);
  v = dpp_fadd<0x140>(v);
  v = dpp_fadd<0x142>(v);
  v = dpp_fadd<0x143>(v);
  return v;  // lane 63 holds the total
}
__device__ __forceinline__ float dpp_sum16(float v) {
  v = dpp_fadd<0xB1>(v);
  v = dpp_fadd<0x4E>(v);
  v = dpp_fadd<0x141>(v);
  v = dpp_fadd<0x140>(v);
  return v;
}

// ---------------- bf16 split helpers (RNE) ----------------
__device__ __forceinline__ ushort bf16hi(float x) {
  unsigned u = __float_as_uint(x);
  unsigned r = u + 0x7FFFu + ((u >> 16) & 1u);
  return (ushort)(r >> 16);
}
__device__ __forceinline__ float bf16tof(ushort u) {
  return __uint_as_float(((unsigned)u) << 16);
}
// split 8 floats -> h-chunk (uint4 of 8 bf16) + l-chunk
__device__ __forceinline__ void split8(const float* xs, uint4& hv, uint4& lv) {
  unsigned h[8], l[8];
#pragma unroll
  for (int j = 0; j < 8; ++j) {
    const ushort hh = bf16hi(xs[j]);
    h[j] = hh;
    l[j] = bf16hi(xs[j] - bf16tof(hh));
  }
  hv = make_uint4(h[0] | (h[1] << 16), h[2] | (h[3] << 16),
                  h[4] | (h[5] << 16), h[6] | (h[7] << 16));
  lv = make_uint4(l[0] | (l[1] << 16), l[2] | (l[3] << 16),
                  l[4] | (l[5] << 16), l[6] | (l[7] << 16));
}
__device__ __forceinline__ short8v u4v(const uint4& x) {
  U8 t;
  t.u[0] = x.x; t.u[1] = x.y; t.u[2] = x.z; t.u[3] = x.w;
  return t.v;
}

// async global->LDS, 16B per lane; LDS dest is wave-uniform base + lane*16
__device__ __forceinline__ void gload_lds16(const void* g, void* l) {
  __builtin_amdgcn_global_load_lds(
      (const __attribute__((address_space(1))) unsigned int*)g,
      (__attribute__((address_space(3))) unsigned int*)l, 16, 0, 0);
}

// ---- W transpose + split to interleaved-slice layout:
// Wti[n][slice s(32k)] = [h-chunk0..3 | l-chunk0..3], 128 B per slice.
__global__ __launch_bounds__(256) void wprep2_k(const float* __restrict__ W,
                                                char* __restrict__ Wti, int K,
                                                int N) {
  __shared__ float tile[32][33];
  const int k0 = blockIdx.x * 32, n0 = blockIdx.y * 32;
  const int r = threadIdx.x >> 5, c = threadIdx.x & 31;
#pragma unroll
  for (int i = 0; i < 4; ++i)
    tile[r + i * 8][c] = W[(size_t)(k0 + r + i * 8) * N + n0 + c];
  __syncthreads();
  if (threadIdx.x < 128) {
    const int gn = threadIdx.x & 31, gk = threadIdx.x >> 5;  // gk 0..3
    float xs[8];
#pragma unroll
    for (int i = 0; i < 8; ++i) xs[i] = tile[gk * 8 + i][gn];
    uint4 hv, lv;
    split8(xs, hv, lv);
    char* dst = Wti + (size_t)(n0 + gn) * K * 4 + (k0 >> 5) * 128 + gk * 16;
    *(uint4*)dst = hv;
    *(uint4*)(dst + 64) = lv;
  }
}

// ---------------- GEMM1: act1p = pack(split(relu(embed[seq]@W1 + b1))) -----
// BK=64, A in REGISTERS (per-thread embed gather + split8, bit-identical to
// the old LDS path), B in 64KB LDS -> 2 blocks/CU guaranteed, barriers
// halved (48 MFMA/wave per barrier-pair). 64x256 tile, grid (512,2).
__global__ __launch_bounds__(512, 2) void gemm1r_k(
    const int* __restrict__ seq, const float* __restrict__ embed,
    const char* __restrict__ w1ti, const float* __restrict__ bias,
    unsigned* __restrict__ outp) {
  __shared__ alignas(16) ushort B[32768];  // 256 rows x 16 chunks x 8 = 64KB
  const int tid = threadIdx.x;
  const int m0 = blockIdx.x * 64, n0 = blockIdx.y * 256;
  const int lane = tid & 63, w = tid >> 6;
  const int wm = (w >> 2) * 32, wn = (w & 3) * 64;
  const int r15 = lane & 15, khalf = lane >> 4;
  // the two embed rows feeding this thread's A-fragments
  const int sq0 = seq[m0 + wm + r15];
  const int sq1 = seq[m0 + wm + 16 + r15];

  f32x4 acc[2][4];
#pragma unroll
  for (int i = 0; i < 2; ++i)
#pragma unroll
    for (int j = 0; j < 4; ++j) acc[i][j] = (f32x4){0.f, 0.f, 0.f, 0.f};

#pragma unroll 1
  for (int kg = 0; kg < 4; ++kg) {
    // stage B: 4096 chunks (256 rows x 16), 8 gloads/thread
#pragma unroll
    for (int i = 0; i < 8; ++i) {
      const int cb = i * 512 + w * 64;
      const int c = cb + lane;
      const int row = c >> 4;
      const int pc = c & 15;
      const int lc = pc ^ (row & 7);  // inverse swizzle (low-3-bit XOR)
      gload_lds16(w1ti + (size_t)(n0 + row) * 1024 + kg * 256 + lc * 16,
                  &B[cb * 8]);
    }
    // A frags in registers: t rows x ks subtiles; gather fp32 + split
    short8v ahf[2][2], alf[2][2];
#pragma unroll
    for (int t = 0; t < 2; ++t) {
      const int sr = t ? sq1 : sq0;
#pragma unroll
      for (int ks = 0; ks < 2; ++ks) {
        const float* ap =
            embed + (size_t)sr * 256 + kg * 64 + ks * 32 + khalf * 8;
        const float4 x0 = *(const float4*)ap;
        const float4 x1 = *(const float4*)(ap + 4);
        const float xs[8] = {x0.x, x0.y, x0.z, x0.w, x1.x, x1.y, x1.z, x1.w};
        uint4 hv, lv;
        split8(xs, hv, lv);
        ahf[t][ks] = u4v(hv);
        alf[t][ks] = u4v(lv);
      }
    }
    __syncthreads();
#pragma unroll
    for (int ks = 0; ks < 2; ++ks) {
      short8v bhf[4], blf[4];
#pragma unroll
      for (int t = 0; t < 4; ++t) {
        const int rb = wn + t * 16 + r15;
        const int r7 = rb & 7;
        bhf[t] = *(const short8v*)&B[(rb * 16 + ((ks * 8 + khalf) ^ r7)) * 8];
        blf[t] =
            *(const short8v*)&B[(rb * 16 + ((ks * 8 + 4 + khalf) ^ r7)) * 8];
      }
#pragma unroll
      for (int mi = 0; mi < 2; ++mi)
#pragma unroll
        for (int ni = 0; ni < 4; ++ni) {
          acc[mi][ni] = __builtin_amdgcn_mfma_f32_16x16x32_bf16(
              ahf[mi][ks], bhf[ni], acc[mi][ni], 0, 0, 0);
          acc[mi][ni] = __builtin_amdgcn_mfma_f32_16x16x32_bf16(
              ahf[mi][ks], blf[ni], acc[mi][ni], 0, 0, 0);
          acc[mi][ni] = __builtin_amdgcn_mfma_f32_16x16x32_bf16(
              alf[mi][ks], bhf[ni], acc[mi][ni], 0, 0, 0);
        }
    }
    __syncthreads();
  }
  // epilogue: relu(acc+b) -> packed u32 (coalesced)
#pragma unroll
  for (int ni = 0; ni < 4; ++ni) {
    const int n = n0 + wn + ni * 16 + r15;
    const float bv = bias[n];
#pragma unroll
    for (int mi = 0; mi < 2; ++mi) {
      const int mbase = m0 + wm + mi * 16 + khalf * 4;
#pragma unroll
      for (int j = 0; j < 4; ++j) {
        const float t = fmaxf(acc[mi][ni][j] + bv, 0.f);
        const ushort h = bf16hi(t);
        const ushort l = bf16hi(t - bf16tof(h));
        outp[(size_t)(mbase + j) * 512 + n] = (unsigned)h | ((unsigned)l << 16);
      }
    }
  }
}

// ---------------- fused GEMM2 + residual + LN + gate/dsc -------------------
// BK=64, A (packed act1p) in REGISTERS via direct uint4 loads + in-reg
// unpack (bit-identical), B 64KB LDS -> 2 blocks/CU. Epilogue scratch
// overlays the dead B buffer; params/seq re-read from global.
__global__ __launch_bounds__(512, 2) void gemm2r_k(
    const unsigned* __restrict__ Ap, const char* __restrict__ w2ti,
    const float* __restrict__ b2, const int* __restrict__ seq,
    const float* __restrict__ embed, const float* __restrict__ gamma,
    const float* __restrict__ beta, const float* __restrict__ Wg,
    const float* __restrict__ bg, const float* __restrict__ Wd,
    const float* __restrict__ bd, float* __restrict__ X,
    int* __restrict__ wbit, float* __restrict__ dsc) {
  __shared__ alignas(16) ushort B[32768];  // 64KB; overlaid by epilogue
  const int tid = threadIdx.x;
  const int m0 = blockIdx.x * 64;
  const int lane = tid & 63, w = tid >> 6;
  const int wm = (w >> 2) * 32, wn = (w & 3) * 64;
  const int r15 = lane & 15, khalf = lane >> 4;
  const int rowA0 = m0 + wm + r15;
  const int rowA1 = m0 + wm + 16 + r15;

  f32x4 acc[2][4];
#pragma unroll
  for (int i = 0; i < 2; ++i)
#pragma unroll
    for (int j = 0; j < 4; ++j) acc[i][j] = (f32x4){0.f, 0.f, 0.f, 0.f};

#pragma unroll 1
  for (int kg = 0; kg < 8; ++kg) {
    // stage B: 4096 chunks (256 n-rows x 16), 8 gloads/thread
#pragma unroll
    for (int i = 0; i < 8; ++i) {
      const int cb = i * 512 + w * 64;
      const int c = cb + lane;
      const int row = c >> 4;
      const int pc = c & 15;
      const int lc = pc ^ (row & 7);
      gload_lds16(w2ti + (size_t)row * 2048 + kg * 256 + lc * 16, &B[cb * 8]);
    }
    // A frags in registers: direct packed loads + unpack (bit-identical)
    short8v ahf[2][2], alf[2][2];
#pragma unroll
    for (int t = 0; t < 2; ++t) {
      const int rowA = t ? rowA1 : rowA0;
#pragma unroll
      for (int ks = 0; ks < 2; ++ks) {
        const unsigned* apr =
            Ap + (size_t)rowA * 512 + kg * 64 + ks * 32 + khalf * 8;
        const uint4 ua = *(const uint4*)apr;
        const uint4 ub = *(const uint4*)(apr + 4);
        U8 vh, vl;
        vh.u[0] = (ua.x & 0xffffu) | (ua.y << 16);
        vl.u[0] = (ua.x >> 16) | (ua.y & 0xffff0000u);
        vh.u[1] = (ua.z & 0xffffu) | (ua.w << 16);
        vl.u[1] = (ua.z >> 16) | (ua.w & 0xffff0000u);
        vh.u[2] = (ub.x & 0xffffu) | (ub.y << 16);
        vl.u[2] = (ub.x >> 16) | (ub.y & 0xffff0000u);
        vh.u[3] = (ub.z & 0xffffu) | (ub.w << 16);
        vl.u[3] = (ub.z >> 16) | (ub.w & 0xffff0000u);
        ahf[t][ks] = vh.v;
        alf[t][ks] = vl.v;
      }
    }
    __syncthreads();
#pragma unroll
    for (int ks = 0; ks < 2; ++ks) {
      short8v bhf[4], blf[4];
#pragma unroll
      for (int t = 0; t < 4; ++t) {
        const int rb = wn + t * 16 + r15;
        const int r7 = rb & 7;
        bhf[t] = *(const short8v*)&B[(rb * 16 + ((ks * 8 + khalf) ^ r7)) * 8];
        blf[t] =
            *(const short8v*)&B[(rb * 16 + ((ks * 8 + 4 + khalf) ^ r7)) * 8];
      }
#pragma unroll
      for (int mi = 0; mi < 2; ++mi)
#pragma unroll
        for (int ni = 0; ni < 4; ++ni) {
          acc[mi][ni] = __builtin_amdgcn_mfma_f32_16x16x32_bf16(
              ahf[mi][ks], bhf[ni], acc[mi][ni], 0, 0, 0);
          acc[mi][ni] = __builtin_amdgcn_mfma_f32_16x16x32_bf16(
              ahf[mi][ks], blf[ni], acc[mi][ni], 0, 0, 0);
          acc[mi][ni] = __builtin_amdgcn_mfma_f32_16x16x32_bf16(
              alf[mi][ks], bhf[ni], acc[mi][ni], 0, 0, 0);
        }
    }
    __syncthreads();
  }

  // ---- epilogue: x = (acc + b2) + resid; LN + gate/dsc. Scratch overlays B.
  char* Bc = (char*)B;
  float(*par0)[4] = (float(*)[4])(Bc);           // 1KB
  float(*par1)[4] = (float(*)[4])(Bc + 1024);    // 1KB
  float(*gpar)[4] = (float(*)[4])(Bc + 2048);    // 1KB
  float(*dpar)[4] = (float(*)[4])(Bc + 3072);    // 1KB
  float mu_r[2][4];
#pragma unroll
  for (int mi = 0; mi < 2; ++mi)
#pragma unroll
    for (int j = 0; j < 4; ++j) {
      const int rowl = wm + mi * 16 + khalf * 4 + j;
      const float* ep = embed + (size_t)seq[m0 + rowl] * 256;
#pragma unroll
      for (int ni = 0; ni < 4; ++ni) {
        const int col = wn + ni * 16 + r15;
        float t = acc[mi][ni][j] + b2[col];
        acc[mi][ni][j] = t + ep[col];
      }
      float s = (acc[mi][0][j] + acc[mi][1][j]) + (acc[mi][2][j] + acc[mi][3][j]);
      s = dpp_sum16(s);
      if (r15 == 0) par0[rowl][w & 3] = s;
    }
  __syncthreads();
#pragma unroll
  for (int mi = 0; mi < 2; ++mi)
#pragma unroll
    for (int j = 0; j < 4; ++j) {
      const int rowl = wm + mi * 16 + khalf * 4 + j;
      const float mu = ((par0[rowl][0] + par0[rowl][1]) +
                        (par0[rowl][2] + par0[rowl][3])) * (1.f / 256.f);
      mu_r[mi][j] = mu;
      const float d0 = acc[mi][0][j] - mu, d1 = acc[mi][1][j] - mu;
      const float d2 = acc[mi][2][j] - mu, d3 = acc[mi][3][j] - mu;
      float vv = (d0 * d0 + d1 * d1) + (d2 * d2 + d3 * d3);
      vv = dpp_sum16(vv);
      if (r15 == 0) par1[rowl][w & 3] = vv;
    }
  __syncthreads();
#pragma unroll
  for (int mi = 0; mi < 2; ++mi)
#pragma unroll
    for (int j = 0; j < 4; ++j) {
      const int rowl = wm + mi * 16 + khalf * 4 + j;
      const float mu = mu_r[mi][j];
      const float var = ((par1[rowl][0] + par1[rowl][1]) +
                         (par1[rowl][2] + par1[rowl][3])) * (1.f / 256.f);
      const float rstd = 1.f / sqrtf(var + 1e-5f);
      float ys[4], gw[4], dw[4];
#pragma unroll
      for (int ni = 0; ni < 4; ++ni) {
        const int col = wn + ni * 16 + r15;
        const float y = (acc[mi][ni][j] - mu) * rstd * gamma[col] + beta[col];
        X[(size_t)(m0 + rowl) * 256 + col] = y;
        ys[ni] = y;
        gw[ni] = Wg[col];
        dw[ni] = Wd[col];
      }
      float gp = (ys[0] * gw[0] + ys[1] * gw[1]) + (ys[2] * gw[2] + ys[3] * gw[3]);
      float dp = (ys[0] * dw[0] + ys[1] * dw[1]) + (ys[2] * dw[2] + ys[3] * dw[3]);
      gp = dpp_sum16(gp);
      dp = dpp_sum16(dp);
      if (r15 == 0) {
        gpar[rowl][w & 3] = gp;
        dpar[rowl][w & 3] = dp;
      }
    }
  __syncthreads();
  if (tid < 64) {
    const int row = tid;
    const float gs = ((gpar[row][0] + gpar[row][1]) +
                      (gpar[row][2] + gpar[row][3])) + bg[0];
    const float dsv = ((dpar[row][0] + dpar[row][1]) +
                       (dpar[row][2] + dpar[row][3])) + bd[0];
    float sig;
    if (gs >= 0.f) {
      sig = 1.f / (1.f + expf(-gs));
    } else {
      const float e2 = expf(gs);
      sig = e2 / (1.f + e2);
    }
    wbit[m0 + row] = (sig >= 0.4f) ? 1 : 0;
    dsc[m0 + row] = dsv;
  }
}

// ---------------- strip-parallel rank kernel: grid (8 strips, 32 batches) --
__global__ __launch_bounds__(1024) void rank_k(
    const int* __restrict__ wbit, const float* __restrict__ dsc,
    unsigned* __restrict__ r12) {
  const int b = blockIdx.y;
  const int s0 = blockIdx.x * 128;
  const int tid = threadIdx.x;
  const int lane = tid & 63, wv = tid >> 6;
  __shared__ unsigned long long skey[1024];
  __shared__ int wavecnt[16];
  __shared__ int waveoff[17];

  int flag = 0;
  float d = 0.f;
  if (tid < 1021) {
    flag = wbit[b * 1024 + tid];
    d = dsc[b * 1024 + tid];
  }
  const unsigned long long m = __ballot(flag != 0);
  if (lane == 0) wavecnt[wv] = __popcll(m);
  skey[tid] = ~0ull;
  __syncthreads();
  if (tid == 0) {
    int acc = 0;
    for (int i = 0; i < 16; ++i) { waveoff[i] = acc; acc += wavecnt[i]; }
    waveoff[16] = acc;
  }
  __syncthreads();
  const int W = waveoff[16];
  if (flag) {
    unsigned u = __float_as_uint(d);
    u = (u & 0x80000000u) ? ~u : (u | 0x80000000u);
    const int w = waveoff[wv] + __popcll(m & ((1ull << lane) - 1ull));
    skey[w] = ((unsigned long long)u << 32) | (unsigned)w;
  }
  __syncthreads();
  const unsigned long long ki = skey[tid];  // own key (MAX if tid >= W)
  __syncthreads();
  if (tid == W - 1) skey[tid] = ~0ull;  // exclude last write from ranks
  __syncthreads();

  const int end2 = max(0, W - 257);
  int r1 = 0, r2 = 0;
#pragma unroll 8
  for (int jj = 0; jj < 128; ++jj) {
    const int j = s0 + jj;
    const int lt = skey[j] < ki;
    r1 += lt;
    r2 += (j < end2) ? lt : 0;
  }
  r12[((size_t)b * 8 + blockIdx.x) * 1024 + tid] =
      (unsigned)r1 | ((unsigned)r2 << 16);
}

// ---------------- fused select + attention (ranks from rank_k partials) ----
__global__ __launch_bounds__(1024) void selattn_k(
    const int* __restrict__ wbit, const float* __restrict__ dsc,
    const unsigned* __restrict__ r12, const float* __restrict__ X,
    const float* __restrict__ Wq, const float* __restrict__ bq,
    float* __restrict__ ctx, float* __restrict__ needs_out) {
  const int b = blockIdx.x;
  const int tid = threadIdx.x;
  const int lane = tid & 63, wv = tid >> 6;
  __shared__ int stokl[1024];
  __shared__ int wavecnt[16];
  __shared__ int waveoff[17];
  __shared__ int fcnt_s[16], scnt_s[16];
  __shared__ int foff[16], soff[16];
  __shared__ int ft[64], st[256];
  __shared__ float hl[256], q[256];
  __shared__ float qpart[4][256];
  __shared__ float sc_f[64], at_f[64];
  __shared__ float sc_s[256], at_s[256];
  __shared__ float redm[4], reds[4];
  __shared__ float needs_s;
  __shared__ float cpart[16][256];

  int flag = 0;
  if (tid < 1021) flag = wbit[b * 1024 + tid];
  const unsigned long long m = __ballot(flag != 0);
  if (lane == 0) wavecnt[wv] = __popcll(m);
  __syncthreads();
  if (tid == 0) {
    int acc = 0;
    for (int i = 0; i < 16; ++i) { waveoff[i] = acc; acc += wavecnt[i]; }
    waveoff[16] = acc;
  }
  __syncthreads();
  const int W = waveoff[16];
  if (flag) {
    const int w = waveoff[wv] + __popcll(m & ((1ull << lane) - 1ull));
    stokl[w] = tid;
  }
  __syncthreads();

  int r1 = 0, r2 = 0;
  {
    const unsigned* rp = r12 + (size_t)b * 8192 + tid;
#pragma unroll
    for (int s = 0; s < 8; ++s) {
      const unsigned v = rp[s * 1024];
      r1 += (int)(v & 0xffffu);
      r2 += (int)(v >> 16);
    }
  }
  const int K = W - 64;
  const int end2 = max(0, W - 257);
  bool fastf = false, slowf = false;
  if (tid < W) {
    const bool isLast = (tid == W - 1);
    const bool inEK = (!isLast) && (r1 < K);
    const bool inE2 = (tid < end2) && (r2 < K - 256);
    fastf = isLast || (!isLast && r1 >= K);
    slowf = inEK && !inE2;
  }

  const unsigned long long mf = __ballot(fastf);
  const unsigned long long ms = __ballot(slowf);
  if (lane == 0) { fcnt_s[wv] = __popcll(mf); scnt_s[wv] = __popcll(ms); }
  __syncthreads();
  if (tid == 0) {
    int a = 0, c = 0;
    for (int i = 0; i < 16; ++i) {
      foff[i] = a; a += fcnt_s[i];
      soff[i] = c; c += scnt_s[i];
    }
  }
  __syncthreads();
  if (fastf) {
    const int p = foff[wv] + __popcll(mf & ((1ull << lane) - 1ull));
    ft[p] = stokl[tid];
  }
  if (slowf) {
    const int p = soff[wv] + __popcll(ms & ((1ull << lane) - 1ull));
    st[p] = stokl[tid];
  }
  const int nf = min(W, 64);
  const int ns = min(max(K, 0), 256);

  // ---- phase 2: attention ----
  const float* Xb = X + (size_t)b * 1024 * 256;
  if (tid < 256) hl[tid] = Xb[(size_t)1023 * 256 + tid];
  __syncthreads();

  {
    const int col = tid & 255, kc = tid >> 8;
    float a = 0.f;
    const float* wp = Wq + (size_t)(kc * 64) * 256 + col;
#pragma unroll 4
    for (int k = 0; k < 64; ++k) a = fmaf(hl[kc * 64 + k], wp[(size_t)k * 256], a);
    qpart[kc][col] = a;
  }
  __syncthreads();
  if (tid < 256)
    q[tid] = ((qpart[0][tid] + qpart[1][tid]) + qpart[2][tid]) + qpart[3][tid] +
             bq[tid];
  __syncthreads();

  const float4 qq = *(const float4*)(q + lane * 4);
#pragma unroll 2
  for (int i = 0; i < 20; ++i) {
    const int r = wv + 16 * i;
    bool valid;
    int tok;
    if (r < 64) { valid = r < nf; tok = valid ? ft[r] : 0; }
    else        { valid = (r - 64) < ns; tok = valid ? st[r - 64] : 0; }
    float sc = NEGV;
    if (valid) {
      const float4 xr = *(const float4*)(Xb + (size_t)tok * 256 + lane * 4);
      float p = (xr.x * qq.x + xr.y * qq.y) + (xr.z * qq.z + xr.w * qq.w);
      sc = dpp_sum63(p);
    }
    if (lane == 63) {
      if (r < 64) sc_f[r] = sc;
      else sc_s[r - 64] = sc;
    }
  }
  __syncthreads();

  if (wv < 4) {
    float s = sc_s[tid];
    float mx = wred_max(s);
    if (lane == 0) redm[wv] = mx;
  } else if (wv == 8) {
    float s = sc_f[lane];
    float mx = wred_max(s);
    float e = expf(s - mx);
    float sm = wred_sum(e);
    float a = e / sm;
    at_f[lane] = a;
    float ma = wred_max(a);
    if (lane == 0) needs_s = (ma < 0.3f) ? 1.f : 0.f;
  }
  __syncthreads();
  if (wv < 4) {
    float s = sc_s[tid];
    float mx = fmaxf(fmaxf(redm[0], redm[1]), fmaxf(redm[2], redm[3]));
    float e = expf(s - mx);
    float sm = wred_sum(e);
    if (lane == 0) reds[wv] = sm;
    at_s[tid] = e;
  }
  __syncthreads();
  if (tid < 256) {
    float sm = (reds[0] + reds[1]) + (reds[2] + reds[3]);
    at_s[tid] = at_s[tid] / sm;
  }
  __syncthreads();

  const float needs = needs_s;
  float4 cp = {0.f, 0.f, 0.f, 0.f};
#pragma unroll 2
  for (int i = 0; i < 20; ++i) {
    const int r = wv + 16 * i;
    bool valid;
    int tok;
    float a;
    if (r < 64) { valid = r < nf; tok = valid ? ft[r] : 0; a = at_f[r]; }
    else {
      valid = (r - 64) < ns;
      tok = valid ? st[r - 64] : 0;
      a = needs * at_s[r - 64];
    }
    if (valid) {
      const float4 xr = *(const float4*)(Xb + (size_t)tok * 256 + lane * 4);
      cp.x = fmaf(a, xr.x, cp.x);
      cp.y = fmaf(a, xr.y, cp.y);
      cp.z = fmaf(a, xr.z, cp.z);
      cp.w = fmaf(a, xr.w, cp.w);
    }
  }
  *(float4*)&cpart[wv][lane * 4] = cp;
  __syncthreads();
  if (tid < 256) {
    float c = 0.f;
#pragma unroll
    for (int w = 0; w < 16; ++w) c += cpart[w][tid];
    ctx[b * 256 + tid] = c;
  }
  if (tid == 0) needs_out[b] = needs;
}

// ---------------- logits: grid (125,4), 8 batches, float4 LDS reads --------
__global__ __launch_bounds__(256) void logits5_k(
    const float* __restrict__ ctx, const float* __restrict__ Wo,
    const float* __restrict__ bo, float* __restrict__ out) {
  __shared__ float cs[256 * 8];  // [h][bb]
  const int tid = threadIdx.x;
  const int b0 = blockIdx.y * 8;
  for (int i = tid; i < 2048; i += 256) {
    int bb = i & 7, hh = i >> 3;
    cs[hh * 8 + bb] = ctx[(b0 + bb) * 256 + hh];
  }
  __syncthreads();
  const int v = blockIdx.x * 256 + tid;
  float acc[8] = {0.f, 0.f, 0.f, 0.f, 0.f, 0.f, 0.f, 0.f};
  for (int h0 = 0; h0 < 256; h0 += 16) {
    float wv[16];
#pragma unroll
    for (int u = 0; u < 16; ++u) wv[u] = Wo[(size_t)(h0 + u) * 32000 + v];
#pragma unroll
    for (int u = 0; u < 16; ++u) {
      const float4 c0 = *(const float4*)&cs[(h0 + u) * 8];
      const float4 c1 = *(const float4*)&cs[(h0 + u) * 8 + 4];
      acc[0] = fmaf(c0.x, wv[u], acc[0]);
      acc[1] = fmaf(c0.y, wv[u], acc[1]);
      acc[2] = fmaf(c0.z, wv[u], acc[2]);
      acc[3] = fmaf(c0.w, wv[u], acc[3]);
      acc[4] = fmaf(c1.x, wv[u], acc[4]);
      acc[5] = fmaf(c1.y, wv[u], acc[5]);
      acc[6] = fmaf(c1.z, wv[u], acc[6]);
      acc[7] = fmaf(c1.w, wv[u], acc[7]);
    }
  }
  const float bv = bo[v];
#pragma unroll
  for (int bb = 0; bb < 8; ++bb)
    out[(size_t)(b0 + bb) * 32000 + v] = acc[bb] + bv;
}

extern "C" void kernel_launch(void* const* d_in, const int* in_sizes, int n_in,
                              void* d_out, int out_size, void* d_ws,
                              size_t ws_size, hipStream_t stream) {
  const int* seq = (const int*)d_in[0];
  const float* embed = (const float*)d_in[1];
  const float* W1 = (const float*)d_in[2];
  const float* b1 = (const float*)d_in[3];
  const float* W2 = (const float*)d_in[4];
  const float* b2 = (const float*)d_in[5];
  const float* gamma = (const float*)d_in[6];
  const float* beta = (const float*)d_in[7];
  const float* Wg = (const float*)d_in[8];
  const float* bg = (const float*)d_in[9];
  const float* Wd = (const float*)d_in[10];
  const float* bd = (const float*)d_in[11];
  const float* Wq = (const float*)d_in[12];
  const float* bq = (const float*)d_in[13];
  const float* Wo = (const float*)d_in[14];
  const float* bo = (const float*)d_in[15];
  float* out = (float*)d_out;

  char* wsb = (char*)d_ws;
  char* w1ti = wsb;                        // 512*256*4 = 512 KiB
  char* w2ti = wsb + 524288;               // 256*512*4 = 512 KiB
  int* wbit = (int*)(wsb + 1048576);       // 32768*4
  float* dscp = (float*)(wsb + 1179648);
  float* ctxp = (float*)(wsb + 1310720);   // 32*256*4
  unsigned* r12p = (unsigned*)(wsb + 1343488);  // 32*8*1024*4 = 1 MiB
  const size_t base = 2392064;

  // full mode needs base + 64M (act1p) + 32M (X) ~= 99 MB
  const int nch = (ws_size >= (size_t)106000000) ? 1 : 2;
  const int rows = 32768 / nch;
  const size_t actsz = (size_t)rows * 512 * 4;
  unsigned* act1p = (unsigned*)(wsb + base);
  float* X = (float*)(wsb + base + actsz);

  dim3 blk(256);
  wprep2_k<<<dim3(8, 16), blk, 0, stream>>>(W1, w1ti, 256, 512);
  wprep2_k<<<dim3(16, 8), blk, 0, stream>>>(W2, w2ti, 512, 256);

  for (int c = 0; c < nch; ++c) {
    const int* seqc = seq + c * rows;
    gemm1r_k<<<dim3(rows / 64, 2), dim3(512), 0, stream>>>(seqc, embed, w1ti,
                                                           b1, act1p);
    gemm2r_k<<<dim3(rows / 64), dim3(512), 0, stream>>>(
        act1p, w2ti, b2, seqc, embed, gamma, beta, Wg, bg, Wd, bd,
        X + (size_t)c * rows * 256, wbit + c * rows, dscp + c * rows);
  }

  rank_k<<<dim3(8, 32), dim3(1024), 0, stream>>>(wbit, dscp, r12p);
  selattn_k<<<32, dim3(1024), 0, stream>>>(wbit, dscp, r12p, X, Wq, bq, ctxp,
                                           out + (size_t)32 * 32000);
  logits5_k<<<dim3(125, 4), blk, 0, stream>>>(ctxp, Wo, bo, out);
}

// Round 19
// 154.483 us; speedup vs baseline: 1.2979x; 1.2979x over previous
//
#include <hip/hip_runtime.h>
#include <hip/hip_bf16.h>
#include <cstdint>

#define NEGV -1e9f

typedef __attribute__((ext_vector_type(8))) short short8v;  // 8 bf16 = 4 VGPR
typedef __attribute__((ext_vector_type(4))) float f32x4;

union U8 {
  unsigned u[4];
  short8v v;
};

// ---------------- wave helpers (wave64) ----------------
__device__ __forceinline__ float wred_sum(float v) {
#pragma unroll
  for (int o = 32; o; o >>= 1) v += __shfl_xor(v, o);
  return v;
}
__device__ __forceinline__ float wred_max(float v) {
#pragma unroll
  for (int o = 32; o; o >>= 1) v = fmaxf(v, __shfl_xor(v, o));
  return v;
}
template <int CTRL>
__device__ __forceinline__ float dpp_fadd(float x) {
  int xi = __float_as_int(x);
  int yi = __builtin_amdgcn_update_dpp(xi, xi, CTRL, 0xF, 0xF, false);
  return x + __int_as_float(yi);
}
__device__ __forceinline__ float dpp_sum63(float v) {
  v = dpp_fadd<0xB1>(v);
  v = dpp_fadd<0x4E>(v);
  v = dpp_fadd<0x141>(v);
  v = dpp_fadd<0x140>(v);
  v = dpp_fadd<0x142>(v);
  v = dpp_fadd<0x143>(v);
  return v;  // lane 63 holds the total
}
__device__ __forceinline__ float dpp_sum16(float v) {
  v = dpp_fadd<0xB1>(v);
  v = dpp_fadd<0x4E>(v);
  v = dpp_fadd<0x141>(v);
  v = dpp_fadd<0x140>(v);
  return v;
}

// ---------------- bf16 split helpers (RNE) ----------------
__device__ __forceinline__ ushort bf16hi(float x) {
  unsigned u = __float_as_uint(x);
  unsigned r = u + 0x7FFFu + ((u >> 16) & 1u);
  return (ushort)(r >> 16);
}
__device__ __forceinline__ float bf16tof(ushort u) {
  return __uint_as_float(((unsigned)u) << 16);
}
// split 8 floats -> h-chunk (uint4 of 8 bf16) + l-chunk
__device__ __forceinline__ void split8(const float* xs, uint4& hv, uint4& lv) {
  unsigned h[8], l[8];
#pragma unroll
  for (int j = 0; j < 8; ++j) {
    const ushort hh = bf16hi(xs[j]);
    h[j] = hh;
    l[j] = bf16hi(xs[j] - bf16tof(hh));
  }
  hv = make_uint4(h[0] | (h[1] << 16), h[2] | (h[3] << 16),
                  h[4] | (h[5] << 16), h[6] | (h[7] << 16));
  lv = make_uint4(l[0] | (l[1] << 16), l[2] | (l[3] << 16),
                  l[4] | (l[5] << 16), l[6] | (l[7] << 16));
}

// async global->LDS, 16B per lane; LDS dest is wave-uniform base + lane*16
__device__ __forceinline__ void gload_lds16(const void* g, void* l) {
  __builtin_amdgcn_global_load_lds(
      (const __attribute__((address_space(1))) unsigned int*)g,
      (__attribute__((address_space(3))) unsigned int*)l, 16, 0, 0);
}

// ---- W transpose + split to interleaved-slice layout:
// Wti[n][slice s(32k)] = [h-chunk0..3 | l-chunk0..3], 128 B per slice.
__global__ __launch_bounds__(256) void wprep2_k(const float* __restrict__ W,
                                                char* __restrict__ Wti, int K,
                                                int N) {
  __shared__ float tile[32][33];
  const int k0 = blockIdx.x * 32, n0 = blockIdx.y * 32;
  const int r = threadIdx.x >> 5, c = threadIdx.x & 31;
#pragma unroll
  for (int i = 0; i < 4; ++i)
    tile[r + i * 8][c] = W[(size_t)(k0 + r + i * 8) * N + n0 + c];
  __syncthreads();
  if (threadIdx.x < 128) {
    const int gn = threadIdx.x & 31, gk = threadIdx.x >> 5;  // gk 0..3
    float xs[8];
#pragma unroll
    for (int i = 0; i < 8; ++i) xs[i] = tile[gk * 8 + i][gn];
    uint4 hv, lv;
    split8(xs, hv, lv);
    char* dst = Wti + (size_t)(n0 + gn) * K * 4 + (k0 >> 5) * 128 + gk * 16;
    *(uint4*)dst = hv;
    *(uint4*)(dst + 64) = lv;
  }
}

// ---------------- GEMM1: act1p = pack(split(relu(embed[seq]@W1 + b1))) -----
// Round-17 structure (64x256 tile, BK=32, grid (512,2)) with the A-store
// bank conflict fixed: 512 threads x ONE 16B phys chunk (row=tid>>3,
// p=tid&7; logical l=p^r7 -> hv(l) if l<4 else lv(l-4)). Per-wave stores
// cover contiguous 1KB -> conflict-free; stored bytes identical.
__global__ __launch_bounds__(512, 2) void gemm1g_k(
    const int* __restrict__ seq, const float* __restrict__ embed,
    const char* __restrict__ w1ti, const float* __restrict__ bias,
    unsigned* __restrict__ outp) {
  __shared__ alignas(16) ushort A[4096];   // 64 rows x 8 chunks x 8 elems
  __shared__ alignas(16) ushort B[16384];  // 256 rows x 8 chunks
  __shared__ int sidx[64];
  const int tid = threadIdx.x;
  const int m0 = blockIdx.x * 64, n0 = blockIdx.y * 256;
  if (tid < 64) sidx[tid] = seq[m0 + tid];
  __syncthreads();
  const int lane = tid & 63, w = tid >> 6;
  const int wm = (w >> 2) * 32, wn = (w & 3) * 64;
  const int r15 = lane & 15, khalf = lane >> 4;

  f32x4 acc[2][4];
#pragma unroll
  for (int i = 0; i < 2; ++i)
#pragma unroll
    for (int j = 0; j < 4; ++j) acc[i][j] = (f32x4){0.f, 0.f, 0.f, 0.f};

#pragma unroll 1
  for (int s = 0; s < 8; ++s) {
    const size_t sb = (size_t)s * 128;
    {  // A: gather fp32 + split inline, one phys chunk per thread
      const int row = tid >> 3, p = tid & 7;
      const int l = p ^ (row & 7);
      const int g = l & 3;
      const float* ap = embed + (size_t)sidx[row] * 256 + s * 32 + g * 8;
      const float4 x0 = *(const float4*)ap;
      const float4 x1 = *(const float4*)(ap + 4);
      const float xs[8] = {x0.x, x0.y, x0.z, x0.w, x1.x, x1.y, x1.z, x1.w};
      uint4 hv, lv;
      split8(xs, hv, lv);
      *(uint4*)&A[(row * 8 + p) * 8] = (l < 4) ? hv : lv;
    }
#pragma unroll
    for (int i = 0; i < 4; ++i) {  // B: 2048 chunks, 4/thread
      const int cb = i * 512 + w * 64;
      const int c = cb + lane;
      const int row = c >> 3;
      const int lc = (c & 7) ^ (row & 7);
      gload_lds16(w1ti + (size_t)(n0 + row) * 1024 + sb + lc * 16,
                  &B[cb * 8]);
    }
    __syncthreads();
    short8v ahf[2], alf[2], bhf[4], blf[4];
#pragma unroll
    for (int t = 0; t < 2; ++t) {
      const int ra = wm + t * 16 + r15;
      ahf[t] = *(const short8v*)&A[(ra * 8 + (khalf ^ (ra & 7))) * 8];
      alf[t] = *(const short8v*)&A[(ra * 8 + ((4 | khalf) ^ (ra & 7))) * 8];
    }
#pragma unroll
    for (int t = 0; t < 4; ++t) {
      const int rb = wn + t * 16 + r15;
      bhf[t] = *(const short8v*)&B[(rb * 8 + (khalf ^ (rb & 7))) * 8];
      blf[t] = *(const short8v*)&B[(rb * 8 + ((4 | khalf) ^ (rb & 7))) * 8];
    }
#pragma unroll
    for (int mi = 0; mi < 2; ++mi)
#pragma unroll
      for (int ni = 0; ni < 4; ++ni) {
        acc[mi][ni] = __builtin_amdgcn_mfma_f32_16x16x32_bf16(
            ahf[mi], bhf[ni], acc[mi][ni], 0, 0, 0);
        acc[mi][ni] = __builtin_amdgcn_mfma_f32_16x16x32_bf16(
            ahf[mi], blf[ni], acc[mi][ni], 0, 0, 0);
        acc[mi][ni] = __builtin_amdgcn_mfma_f32_16x16x32_bf16(
            alf[mi], bhf[ni], acc[mi][ni], 0, 0, 0);
      }
    __syncthreads();
  }
  // epilogue: relu(acc+b) -> packed u32 (coalesced)
#pragma unroll
  for (int ni = 0; ni < 4; ++ni) {
    const int n = n0 + wn + ni * 16 + r15;
    const float bv = bias[n];
#pragma unroll
    for (int mi = 0; mi < 2; ++mi) {
      const int mbase = m0 + wm + mi * 16 + khalf * 4;
#pragma unroll
      for (int j = 0; j < 4; ++j) {
        const float t = fmaxf(acc[mi][ni][j] + bv, 0.f);
        const ushort h = bf16hi(t);
        const ushort l = bf16hi(t - bf16tof(h));
        outp[(size_t)(mbase + j) * 512 + n] = (unsigned)h | ((unsigned)l << 16);
      }
    }
  }
}

// ---------------- fused GEMM2 + residual + LN + gate/dsc, 64-row tile ------
__global__ __launch_bounds__(512, 2) void gemm2i_k(
    const unsigned* __restrict__ Ap, const char* __restrict__ w2ti,
    const float* __restrict__ b2, const int* __restrict__ seq,
    const float* __restrict__ embed, const float* __restrict__ gamma,
    const float* __restrict__ beta, const float* __restrict__ Wg,
    const float* __restrict__ bg, const float* __restrict__ Wd,
    const float* __restrict__ bd, float* __restrict__ X,
    int* __restrict__ wbit, float* __restrict__ dsc) {
  __shared__ alignas(16) unsigned Apk[2048];  // 64 rows x 8 chunks(4 u32)
  __shared__ alignas(16) ushort B[16384];     // 256 rows x 8 chunks
  __shared__ float par0[64][4], par1[64][4], gpar[64][4], dpar[64][4];
  __shared__ float g_s[256], be_s[256], wg_s[256], wd_s[256], b2_s[256];
  __shared__ int sidx[64];
  const int tid = threadIdx.x;
  const int m0 = blockIdx.x * 64;
  if (tid < 64) sidx[tid] = seq[m0 + tid];
  if (tid >= 256) {
    const int c = tid - 256;
    g_s[c] = gamma[c];
    be_s[c] = beta[c];
    wg_s[c] = Wg[c];
    wd_s[c] = Wd[c];
    b2_s[c] = b2[c];
  }
  const int lane = tid & 63, w = tid >> 6;
  const int wm = (w >> 2) * 32, wn = (w & 3) * 64;
  const int r15 = lane & 15, khalf = lane >> 4;

  f32x4 acc[2][4];
#pragma unroll
  for (int i = 0; i < 2; ++i)
#pragma unroll
    for (int j = 0; j < 4; ++j) acc[i][j] = (f32x4){0.f, 0.f, 0.f, 0.f};

#pragma unroll 1
  for (int s = 0; s < 16; ++s) {
    {  // A packed: 512 chunks, 1/thread
      const int cb = w * 64;
      const int c = cb + lane;
      const int row = c >> 3;
      const int lc = (c & 7) ^ (row & 7);
      gload_lds16(Ap + (size_t)(m0 + row) * 512 + s * 32 + lc * 4,
                  &Apk[cb * 4]);
    }
    const size_t sb = (size_t)s * 128;
#pragma unroll
    for (int i = 0; i < 4; ++i) {  // B: 2048 chunks
      const int cb = i * 512 + w * 64;
      const int c = cb + lane;
      const int row = c >> 3;
      const int lc = (c & 7) ^ (row & 7);
      gload_lds16(w2ti + (size_t)row * 2048 + sb + lc * 16, &B[cb * 8]);
    }
    __syncthreads();
    short8v ahf[2], alf[2], bhf[4], blf[4];
#pragma unroll
    for (int t = 0; t < 2; ++t) {
      const int ra = wm + t * 16 + r15;
      const int r7 = ra & 7;
      const uint4 ua = *(const uint4*)&Apk[(ra * 8 + ((khalf * 2) ^ r7)) * 4];
      const uint4 ub =
          *(const uint4*)&Apk[(ra * 8 + ((khalf * 2 + 1) ^ r7)) * 4];
      U8 vh, vl;
      vh.u[0] = (ua.x & 0xffffu) | (ua.y << 16);
      vl.u[0] = (ua.x >> 16) | (ua.y & 0xffff0000u);
      vh.u[1] = (ua.z & 0xffffu) | (ua.w << 16);
      vl.u[1] = (ua.z >> 16) | (ua.w & 0xffff0000u);
      vh.u[2] = (ub.x & 0xffffu) | (ub.y << 16);
      vl.u[2] = (ub.x >> 16) | (ub.y & 0xffff0000u);
      vh.u[3] = (ub.z & 0xffffu) | (ub.w << 16);
      vl.u[3] = (ub.z >> 16) | (ub.w & 0xffff0000u);
      ahf[t] = vh.v;
      alf[t] = vl.v;
    }
#pragma unroll
    for (int t = 0; t < 4; ++t) {
      const int rb = wn + t * 16 + r15;
      bhf[t] = *(const short8v*)&B[(rb * 8 + (khalf ^ (rb & 7))) * 8];
      blf[t] = *(const short8v*)&B[(rb * 8 + ((4 | khalf) ^ (rb & 7))) * 8];
    }
#pragma unroll
    for (int mi = 0; mi < 2; ++mi)
#pragma unroll
      for (int ni = 0; ni < 4; ++ni) {
        acc[mi][ni] = __builtin_amdgcn_mfma_f32_16x16x32_bf16(
            ahf[mi], bhf[ni], acc[mi][ni], 0, 0, 0);
        acc[mi][ni] = __builtin_amdgcn_mfma_f32_16x16x32_bf16(
            ahf[mi], blf[ni], acc[mi][ni], 0, 0, 0);
        acc[mi][ni] = __builtin_amdgcn_mfma_f32_16x16x32_bf16(
            alf[mi], bhf[ni], acc[mi][ni], 0, 0, 0);
      }
    __syncthreads();
  }

  // ---- epilogue: x = (acc + b2) + resid; then LN + gate/dsc ----
  float mu_r[2][4];
#pragma unroll
  for (int mi = 0; mi < 2; ++mi)
#pragma unroll
    for (int j = 0; j < 4; ++j) {
      const int rowl = wm + mi * 16 + khalf * 4 + j;
      const float* ep = embed + (size_t)sidx[rowl] * 256;
#pragma unroll
      for (int ni = 0; ni < 4; ++ni) {
        const int col = wn + ni * 16 + r15;
        float t = acc[mi][ni][j] + b2_s[col];
        acc[mi][ni][j] = t + ep[col];
      }
      float s = (acc[mi][0][j] + acc[mi][1][j]) + (acc[mi][2][j] + acc[mi][3][j]);
      s = dpp_sum16(s);
      if (r15 == 0) par0[rowl][w & 3] = s;
    }
  __syncthreads();
#pragma unroll
  for (int mi = 0; mi < 2; ++mi)
#pragma unroll
    for (int j = 0; j < 4; ++j) {
      const int rowl = wm + mi * 16 + khalf * 4 + j;
      const float mu = ((par0[rowl][0] + par0[rowl][1]) +
                        (par0[rowl][2] + par0[rowl][3])) * (1.f / 256.f);
      mu_r[mi][j] = mu;
      const float d0 = acc[mi][0][j] - mu, d1 = acc[mi][1][j] - mu;
      const float d2 = acc[mi][2][j] - mu, d3 = acc[mi][3][j] - mu;
      float vv = (d0 * d0 + d1 * d1) + (d2 * d2 + d3 * d3);
      vv = dpp_sum16(vv);
      if (r15 == 0) par1[rowl][w & 3] = vv;
    }
  __syncthreads();
#pragma unroll
  for (int mi = 0; mi < 2; ++mi)
#pragma unroll
    for (int j = 0; j < 4; ++j) {
      const int rowl = wm + mi * 16 + khalf * 4 + j;
      const float mu = mu_r[mi][j];
      const float var = ((par1[rowl][0] + par1[rowl][1]) +
                         (par1[rowl][2] + par1[rowl][3])) * (1.f / 256.f);
      const float rstd = 1.f / sqrtf(var + 1e-5f);
      float ys[4], gw[4], dw[4];
#pragma unroll
      for (int ni = 0; ni < 4; ++ni) {
        const int col = wn + ni * 16 + r15;
        const float y = (acc[mi][ni][j] - mu) * rstd * g_s[col] + be_s[col];
        X[(size_t)(m0 + rowl) * 256 + col] = y;
        ys[ni] = y;
        gw[ni] = wg_s[col];
        dw[ni] = wd_s[col];
      }
      float gp = (ys[0] * gw[0] + ys[1] * gw[1]) + (ys[2] * gw[2] + ys[3] * gw[3]);
      float dp = (ys[0] * dw[0] + ys[1] * dw[1]) + (ys[2] * dw[2] + ys[3] * dw[3]);
      gp = dpp_sum16(gp);
      dp = dpp_sum16(dp);
      if (r15 == 0) {
        gpar[rowl][w & 3] = gp;
        dpar[rowl][w & 3] = dp;
      }
    }
  __syncthreads();
  if (tid < 64) {
    const int row = tid;
    const float gs = ((gpar[row][0] + gpar[row][1]) +
                      (gpar[row][2] + gpar[row][3])) + bg[0];
    const float dsv = ((dpar[row][0] + dpar[row][1]) +
                       (dpar[row][2] + dpar[row][3])) + bd[0];
    float sig;
    if (gs >= 0.f) {
      sig = 1.f / (1.f + expf(-gs));
    } else {
      const float e2 = expf(gs);
      sig = e2 / (1.f + e2);
    }
    wbit[m0 + row] = (sig >= 0.4f) ? 1 : 0;
    dsc[m0 + row] = dsv;
  }
}

// ---------------- strip-parallel rank kernel: grid (8 strips, 32 batches) --
__global__ __launch_bounds__(1024) void rank_k(
    const int* __restrict__ wbit, const float* __restrict__ dsc,
    unsigned* __restrict__ r12) {
  const int b = blockIdx.y;
  const int s0 = blockIdx.x * 128;
  const int tid = threadIdx.x;
  const int lane = tid & 63, wv = tid >> 6;
  __shared__ unsigned long long skey[1024];
  __shared__ int wavecnt[16];
  __shared__ int waveoff[17];

  int flag = 0;
  float d = 0.f;
  if (tid < 1021) {
    flag = wbit[b * 1024 + tid];
    d = dsc[b * 1024 + tid];
  }
  const unsigned long long m = __ballot(flag != 0);
  if (lane == 0) wavecnt[wv] = __popcll(m);
  skey[tid] = ~0ull;
  __syncthreads();
  if (tid == 0) {
    int acc = 0;
    for (int i = 0; i < 16; ++i) { waveoff[i] = acc; acc += wavecnt[i]; }
    waveoff[16] = acc;
  }
  __syncthreads();
  const int W = waveoff[16];
  if (flag) {
    unsigned u = __float_as_uint(d);
    u = (u & 0x80000000u) ? ~u : (u | 0x80000000u);
    const int w = waveoff[wv] + __popcll(m & ((1ull << lane) - 1ull));
    skey[w] = ((unsigned long long)u << 32) | (unsigned)w;
  }
  __syncthreads();
  const unsigned long long ki = skey[tid];  // own key (MAX if tid >= W)
  __syncthreads();
  if (tid == W - 1) skey[tid] = ~0ull;  // exclude last write from ranks
  __syncthreads();

  const int end2 = max(0, W - 257);
  int r1 = 0, r2 = 0;
#pragma unroll 8
  for (int jj = 0; jj < 128; ++jj) {
    const int j = s0 + jj;
    const int lt = skey[j] < ki;
    r1 += lt;
    r2 += (j < end2) ? lt : 0;
  }
  r12[((size_t)b * 8 + blockIdx.x) * 1024 + tid] =
      (unsigned)r1 | ((unsigned)r2 << 16);
}

// ---------------- fused select + attention (ranks from rank_k partials) ----
__global__ __launch_bounds__(1024) void selattn_k(
    const int* __restrict__ wbit, const float* __restrict__ dsc,
    const unsigned* __restrict__ r12, const float* __restrict__ X,
    const float* __restrict__ Wq, const float* __restrict__ bq,
    float* __restrict__ ctx, float* __restrict__ needs_out) {
  const int b = blockIdx.x;
  const int tid = threadIdx.x;
  const int lane = tid & 63, wv = tid >> 6;
  __shared__ int stokl[1024];
  __shared__ int wavecnt[16];
  __shared__ int waveoff[17];
  __shared__ int fcnt_s[16], scnt_s[16];
  __shared__ int foff[16], soff[16];
  __shared__ int ft[64], st[256];
  __shared__ float hl[256], q[256];
  __shared__ float qpart[4][256];
  __shared__ float sc_f[64], at_f[64];
  __shared__ float sc_s[256], at_s[256];
  __shared__ float redm[4], reds[4];
  __shared__ float needs_s;
  __shared__ float cpart[16][256];

  int flag = 0;
  if (tid < 1021) flag = wbit[b * 1024 + tid];
  const unsigned long long m = __ballot(flag != 0);
  if (lane == 0) wavecnt[wv] = __popcll(m);
  __syncthreads();
  if (tid == 0) {
    int acc = 0;
    for (int i = 0; i < 16; ++i) { waveoff[i] = acc; acc += wavecnt[i]; }
    waveoff[16] = acc;
  }
  __syncthreads();
  const int W = waveoff[16];
  if (flag) {
    const int w = waveoff[wv] + __popcll(m & ((1ull << lane) - 1ull));
    stokl[w] = tid;
  }
  __syncthreads();

  int r1 = 0, r2 = 0;
  {
    const unsigned* rp = r12 + (size_t)b * 8192 + tid;
#pragma unroll
    for (int s = 0; s < 8; ++s) {
      const unsigned v = rp[s * 1024];
      r1 += (int)(v & 0xffffu);
      r2 += (int)(v >> 16);
    }
  }
  const int K = W - 64;
  const int end2 = max(0, W - 257);
  bool fastf = false, slowf = false;
  if (tid < W) {
    const bool isLast = (tid == W - 1);
    const bool inEK = (!isLast) && (r1 < K);
    const bool inE2 = (tid < end2) && (r2 < K - 256);
    fastf = isLast || (!isLast && r1 >= K);
    slowf = inEK && !inE2;
  }

  const unsigned long long mf = __ballot(fastf);
  const unsigned long long ms = __ballot(slowf);
  if (lane == 0) { fcnt_s[wv] = __popcll(mf); scnt_s[wv] = __popcll(ms); }
  __syncthreads();
  if (tid == 0) {
    int a = 0, c = 0;
    for (int i = 0; i < 16; ++i) {
      foff[i] = a; a += fcnt_s[i];
      soff[i] = c; c += scnt_s[i];
    }
  }
  __syncthreads();
  if (fastf) {
    const int p = foff[wv] + __popcll(mf & ((1ull << lane) - 1ull));
    ft[p] = stokl[tid];
  }
  if (slowf) {
    const int p = soff[wv] + __popcll(ms & ((1ull << lane) - 1ull));
    st[p] = stokl[tid];
  }
  const int nf = min(W, 64);
  const int ns = min(max(K, 0), 256);

  // ---- phase 2: attention ----
  const float* Xb = X + (size_t)b * 1024 * 256;
  if (tid < 256) hl[tid] = Xb[(size_t)1023 * 256 + tid];
  __syncthreads();

  {
    const int col = tid & 255, kc = tid >> 8;
    float a = 0.f;
    const float* wp = Wq + (size_t)(kc * 64) * 256 + col;
#pragma unroll 4
    for (int k = 0; k < 64; ++k) a = fmaf(hl[kc * 64 + k], wp[(size_t)k * 256], a);
    qpart[kc][col] = a;
  }
  __syncthreads();
  if (tid < 256)
    q[tid] = ((qpart[0][tid] + qpart[1][tid]) + qpart[2][tid]) + qpart[3][tid] +
             bq[tid];
  __syncthreads();

  const float4 qq = *(const float4*)(q + lane * 4);
#pragma unroll 2
  for (int i = 0; i < 20; ++i) {
    const int r = wv + 16 * i;
    bool valid;
    int tok;
    if (r < 64) { valid = r < nf; tok = valid ? ft[r] : 0; }
    else        { valid = (r - 64) < ns; tok = valid ? st[r - 64] : 0; }
    float sc = NEGV;
    if (valid) {
      const float4 xr = *(const float4*)(Xb + (size_t)tok * 256 + lane * 4);
      float p = (xr.x * qq.x + xr.y * qq.y) + (xr.z * qq.z + xr.w * qq.w);
      sc = dpp_sum63(p);
    }
    if (lane == 63) {
      if (r < 64) sc_f[r] = sc;
      else sc_s[r - 64] = sc;
    }
  }
  __syncthreads();

  if (wv < 4) {
    float s = sc_s[tid];
    float mx = wred_max(s);
    if (lane == 0) redm[wv] = mx;
  } else if (wv == 8) {
    float s = sc_f[lane];
    float mx = wred_max(s);
    float e = expf(s - mx);
    float sm = wred_sum(e);
    float a = e / sm;
    at_f[lane] = a;
    float ma = wred_max(a);
    if (lane == 0) needs_s = (ma < 0.3f) ? 1.f : 0.f;
  }
  __syncthreads();
  if (wv < 4) {
    float s = sc_s[tid];
    float mx = fmaxf(fmaxf(redm[0], redm[1]), fmaxf(redm[2], redm[3]));
    float e = expf(s - mx);
    float sm = wred_sum(e);
    if (lane == 0) reds[wv] = sm;
    at_s[tid] = e;
  }
  __syncthreads();
  if (tid < 256) {
    float sm = (reds[0] + reds[1]) + (reds[2] + reds[3]);
    at_s[tid] = at_s[tid] / sm;
  }
  __syncthreads();

  const float needs = needs_s;
  float4 cp = {0.f, 0.f, 0.f, 0.f};
#pragma unroll 2
  for (int i = 0; i < 20; ++i) {
    const int r = wv + 16 * i;
    bool valid;
    int tok;
    float a;
    if (r < 64) { valid = r < nf; tok = valid ? ft[r] : 0; a = at_f[r]; }
    else {
      valid = (r - 64) < ns;
      tok = valid ? st[r - 64] : 0;
      a = needs * at_s[r - 64];
    }
    if (valid) {
      const float4 xr = *(const float4*)(Xb + (size_t)tok * 256 + lane * 4);
      cp.x = fmaf(a, xr.x, cp.x);
      cp.y = fmaf(a, xr.y, cp.y);
      cp.z = fmaf(a, xr.z, cp.z);
      cp.w = fmaf(a, xr.w, cp.w);
    }
  }
  *(float4*)&cpart[wv][lane * 4] = cp;
  __syncthreads();
  if (tid < 256) {
    float c = 0.f;
#pragma unroll
    for (int w = 0; w < 16; ++w) c += cpart[w][tid];
    ctx[b * 256 + tid] = c;
  }
  if (tid == 0) needs_out[b] = needs;
}

// ---------------- logits: grid (125,4), 8 batches, float4 LDS reads --------
__global__ __launch_bounds__(256) void logits5_k(
    const float* __restrict__ ctx, const float* __restrict__ Wo,
    const float* __restrict__ bo, float* __restrict__ out) {
  __shared__ float cs[256 * 8];  // [h][bb]
  const int tid = threadIdx.x;
  const int b0 = blockIdx.y * 8;
  for (int i = tid; i < 2048; i += 256) {
    int bb = i & 7, hh = i >> 3;
    cs[hh * 8 + bb] = ctx[(b0 + bb) * 256 + hh];
  }
  __syncthreads();
  const int v = blockIdx.x * 256 + tid;
  float acc[8] = {0.f, 0.f, 0.f, 0.f, 0.f, 0.f, 0.f, 0.f};
  for (int h0 = 0; h0 < 256; h0 += 16) {
    float wv[16];
#pragma unroll
    for (int u = 0; u < 16; ++u) wv[u] = Wo[(size_t)(h0 + u) * 32000 + v];
#pragma unroll
    for (int u = 0; u < 16; ++u) {
      const float4 c0 = *(const float4*)&cs[(h0 + u) * 8];
      const float4 c1 = *(const float4*)&cs[(h0 + u) * 8 + 4];
      acc[0] = fmaf(c0.x, wv[u], acc[0]);
      acc[1] = fmaf(c0.y, wv[u], acc[1]);
      acc[2] = fmaf(c0.z, wv[u], acc[2]);
      acc[3] = fmaf(c0.w, wv[u], acc[3]);
      acc[4] = fmaf(c1.x, wv[u], acc[4]);
      acc[5] = fmaf(c1.y, wv[u], acc[5]);
      acc[6] = fmaf(c1.z, wv[u], acc[6]);
      acc[7] = fmaf(c1.w, wv[u], acc[7]);
    }
  }
  const float bv = bo[v];
#pragma unroll
  for (int bb = 0; bb < 8; ++bb)
    out[(size_t)(b0 + bb) * 32000 + v] = acc[bb] + bv;
}

extern "C" void kernel_launch(void* const* d_in, const int* in_sizes, int n_in,
                              void* d_out, int out_size, void* d_ws,
                              size_t ws_size, hipStream_t stream) {
  const int* seq = (const int*)d_in[0];
  const float* embed = (const float*)d_in[1];
  const float* W1 = (const float*)d_in[2];
  const float* b1 = (const float*)d_in[3];
  const float* W2 = (const float*)d_in[4];
  const float* b2 = (const float*)d_in[5];
  const float* gamma = (const float*)d_in[6];
  const float* beta = (const float*)d_in[7];
  const float* Wg = (const float*)d_in[8];
  const float* bg = (const float*)d_in[9];
  const float* Wd = (const float*)d_in[10];
  const float* bd = (const float*)d_in[11];
  const float* Wq = (const float*)d_in[12];
  const float* bq = (const float*)d_in[13];
  const float* Wo = (const float*)d_in[14];
  const float* bo = (const float*)d_in[15];
  float* out = (float*)d_out;

  char* wsb = (char*)d_ws;
  char* w1ti = wsb;                        // 512*256*4 = 512 KiB
  char* w2ti = wsb + 524288;               // 256*512*4 = 512 KiB
  int* wbit = (int*)(wsb + 1048576);       // 32768*4
  float* dscp = (float*)(wsb + 1179648);
  float* ctxp = (float*)(wsb + 1310720);   // 32*256*4
  unsigned* r12p = (unsigned*)(wsb + 1343488);  // 32*8*1024*4 = 1 MiB
  const size_t base = 2392064;

  // full mode needs base + 64M (act1p) + 32M (X) ~= 99 MB
  const int nch = (ws_size >= (size_t)106000000) ? 1 : 2;
  const int rows = 32768 / nch;
  const size_t actsz = (size_t)rows * 512 * 4;
  unsigned* act1p = (unsigned*)(wsb + base);
  float* X = (float*)(wsb + base + actsz);

  dim3 blk(256);
  wprep2_k<<<dim3(8, 16), blk, 0, stream>>>(W1, w1ti, 256, 512);
  wprep2_k<<<dim3(16, 8), blk, 0, stream>>>(W2, w2ti, 512, 256);

  for (int c = 0; c < nch; ++c) {
    const int* seqc = seq + c * rows;
    gemm1g_k<<<dim3(rows / 64, 2), dim3(512), 0, stream>>>(seqc, embed, w1ti,
                                                           b1, act1p);
    gemm2i_k<<<dim3(rows / 64), dim3(512), 0, stream>>>(
        act1p, w2ti, b2, seqc, embed, gamma, beta, Wg, bg, Wd, bd,
        X + (size_t)c * rows * 256, wbit + c * rows, dscp + c * rows);
  }

  rank_k<<<dim3(8, 32), dim3(1024), 0, stream>>>(wbit, dscp, r12p);
  selattn_k<<<32, dim3(1024), 0, stream>>>(wbit, dscp, r12p, X, Wq, bq, ctxp,
                                           out + (size_t)32 * 32000);
  logits5_k<<<dim3(125, 4), blk, 0, stream>>>(ctxp, Wo, bo, out);
}

// Round 20
// 138.769 us; speedup vs baseline: 1.4449x; 1.1132x over previous
//
#include <hip/hip_runtime.h>
#include <hip/hip_bf16.h>
#include <cstdint>

#define NEGV -1e9f

typedef __attribute__((ext_vector_type(8))) short short8v;  // 8 bf16 = 4 VGPR
typedef __attribute__((ext_vector_type(4))) float f32x4;

union U8 {
  unsigned u[4];
  short8v v;
};

// ---------------- wave helpers (wave64) ----------------
__device__ __forceinline__ float wred_sum(float v) {
#pragma unroll
  for (int o = 32; o; o >>= 1) v += __shfl_xor(v, o);
  return v;
}
__device__ __forceinline__ float wred_max(float v) {
#pragma unroll
  for (int o = 32; o; o >>= 1) v = fmaxf(v, __shfl_xor(v, o));
  return v;
}
template <int CTRL>
__device__ __forceinline__ float dpp_fadd(float x) {
  int xi = __float_as_int(x);
  int yi = __builtin_amdgcn_update_dpp(xi, xi, CTRL, 0xF, 0xF, false);
  return x + __int_as_float(yi);
}
__device__ __forceinline__ float dpp_sum63(float v) {
  v = dpp_fadd<0xB1>(v);
  v = dpp_fadd<0x4E>(v);
  v = dpp_fadd<0x141>(v);
  v = dpp_fadd<0x140>(v);
  v = dpp_fadd<0x142>(v);
  v = dpp_fadd<0x143>(v);
  return v;  // lane 63 holds the total
}
__device__ __forceinline__ float dpp_sum16(float v) {
  v = dpp_fadd<0xB1>(v);
  v = dpp_fadd<0x4E>(v);
  v = dpp_fadd<0x141>(v);
  v = dpp_fadd<0x140>(v);
  return v;
}

// ---------------- bf16 split helpers (RNE) ----------------
__device__ __forceinline__ ushort bf16hi(float x) {
  unsigned u = __float_as_uint(x);
  unsigned r = u + 0x7FFFu + ((u >> 16) & 1u);
  return (ushort)(r >> 16);
}
__device__ __forceinline__ float bf16tof(ushort u) {
  return __uint_as_float(((unsigned)u) << 16);
}
// split 8 floats -> h-chunk (uint4 of 8 bf16) + l-chunk
__device__ __forceinline__ void split8(const float* xs, uint4& hv, uint4& lv) {
  unsigned h[8], l[8];
#pragma unroll
  for (int j = 0; j < 8; ++j) {
    const ushort hh = bf16hi(xs[j]);
    h[j] = hh;
    l[j] = bf16hi(xs[j] - bf16tof(hh));
  }
  hv = make_uint4(h[0] | (h[1] << 16), h[2] | (h[3] << 16),
                  h[4] | (h[5] << 16), h[6] | (h[7] << 16));
  lv = make_uint4(l[0] | (l[1] << 16), l[2] | (l[3] << 16),
                  l[4] | (l[5] << 16), l[6] | (l[7] << 16));
}

// async global->LDS, 16B per lane; LDS dest is wave-uniform base + lane*16
__device__ __forceinline__ void gload_lds16(const void* g, void* l) {
  __builtin_amdgcn_global_load_lds(
      (const __attribute__((address_space(1))) unsigned int*)g,
      (__attribute__((address_space(3))) unsigned int*)l, 16, 0, 0);
}

// ---- W transpose + split to interleaved-slice layout:
// Wti[n][slice s(32k)] = [h-chunk0..3 | l-chunk0..3], 128 B per slice.
__global__ __launch_bounds__(256) void wprep2_k(const float* __restrict__ W,
                                                char* __restrict__ Wti, int K,
                                                int N) {
  __shared__ float tile[32][33];
  const int k0 = blockIdx.x * 32, n0 = blockIdx.y * 32;
  const int r = threadIdx.x >> 5, c = threadIdx.x & 31;
#pragma unroll
  for (int i = 0; i < 4; ++i)
    tile[r + i * 8][c] = W[(size_t)(k0 + r + i * 8) * N + n0 + c];
  __syncthreads();
  if (threadIdx.x < 128) {
    const int gn = threadIdx.x & 31, gk = threadIdx.x >> 5;  // gk 0..3
    float xs[8];
#pragma unroll
    for (int i = 0; i < 8; ++i) xs[i] = tile[gk * 8 + i][gn];
    uint4 hv, lv;
    split8(xs, hv, lv);
    char* dst = Wti + (size_t)(n0 + gn) * K * 4 + (k0 >> 5) * 128 + gk * 16;
    *(uint4*)dst = hv;
    *(uint4*)(dst + 64) = lv;
  }
}

// ---------------- GEMM1: act1p = pack(split(relu(embed[seq]@W1 + b1))) -----
// 64x256 tile, grid (512,2). A-stage = inline gather+split (round-17 form,
// the empirical best: 43.6us; two attempted "fixes" both regressed).
__global__ __launch_bounds__(512, 2) void gemm1g_k(
    const int* __restrict__ seq, const float* __restrict__ embed,
    const char* __restrict__ w1ti, const float* __restrict__ bias,
    unsigned* __restrict__ outp) {
  __shared__ alignas(16) ushort A[4096];   // 64 rows x 8 chunks x 8 elems
  __shared__ alignas(16) ushort B[16384];  // 256 rows x 8 chunks
  __shared__ int sidx[64];
  const int tid = threadIdx.x;
  const int m0 = blockIdx.x * 64, n0 = blockIdx.y * 256;
  if (tid < 64) sidx[tid] = seq[m0 + tid];
  __syncthreads();
  const int lane = tid & 63, w = tid >> 6;
  const int wm = (w >> 2) * 32, wn = (w & 3) * 64;
  const int r15 = lane & 15, khalf = lane >> 4;

  f32x4 acc[2][4];
#pragma unroll
  for (int i = 0; i < 2; ++i)
#pragma unroll
    for (int j = 0; j < 4; ++j) acc[i][j] = (f32x4){0.f, 0.f, 0.f, 0.f};

#pragma unroll 1
  for (int s = 0; s < 8; ++s) {
    const size_t sb = (size_t)s * 128;
    if (tid < 256) {  // A: gather fp32 + split inline, (row,q) per thread
      const int row = tid >> 2, q = tid & 3;
      const float* ap = embed + (size_t)sidx[row] * 256 + s * 32 + q * 8;
      const float4 x0 = *(const float4*)ap;
      const float4 x1 = *(const float4*)(ap + 4);
      const float xs[8] = {x0.x, x0.y, x0.z, x0.w, x1.x, x1.y, x1.z, x1.w};
      uint4 hv, lv;
      split8(xs, hv, lv);
      const int r7 = row & 7;
      *(uint4*)&A[(row * 8 + (q ^ r7)) * 8] = hv;
      *(uint4*)&A[(row * 8 + ((4 | q) ^ r7)) * 8] = lv;
    }
#pragma unroll
    for (int i = 0; i < 4; ++i) {  // B: 2048 chunks, 4/thread
      const int cb = i * 512 + w * 64;
      const int c = cb + lane;
      const int row = c >> 3;
      const int lc = (c & 7) ^ (row & 7);
      gload_lds16(w1ti + (size_t)(n0 + row) * 1024 + sb + lc * 16,
                  &B[cb * 8]);
    }
    __syncthreads();
    short8v ahf[2], alf[2], bhf[4], blf[4];
#pragma unroll
    for (int t = 0; t < 2; ++t) {
      const int ra = wm + t * 16 + r15;
      ahf[t] = *(const short8v*)&A[(ra * 8 + (khalf ^ (ra & 7))) * 8];
      alf[t] = *(const short8v*)&A[(ra * 8 + ((4 | khalf) ^ (ra & 7))) * 8];
    }
#pragma unroll
    for (int t = 0; t < 4; ++t) {
      const int rb = wn + t * 16 + r15;
      bhf[t] = *(const short8v*)&B[(rb * 8 + (khalf ^ (rb & 7))) * 8];
      blf[t] = *(const short8v*)&B[(rb * 8 + ((4 | khalf) ^ (rb & 7))) * 8];
    }
#pragma unroll
    for (int mi = 0; mi < 2; ++mi)
#pragma unroll
      for (int ni = 0; ni < 4; ++ni) {
        acc[mi][ni] = __builtin_amdgcn_mfma_f32_16x16x32_bf16(
            ahf[mi], bhf[ni], acc[mi][ni], 0, 0, 0);
        acc[mi][ni] = __builtin_amdgcn_mfma_f32_16x16x32_bf16(
            ahf[mi], blf[ni], acc[mi][ni], 0, 0, 0);
        acc[mi][ni] = __builtin_amdgcn_mfma_f32_16x16x32_bf16(
            alf[mi], bhf[ni], acc[mi][ni], 0, 0, 0);
      }
    __syncthreads();
  }
  // epilogue: relu(acc+b) -> packed u32 (coalesced)
#pragma unroll
  for (int ni = 0; ni < 4; ++ni) {
    const int n = n0 + wn + ni * 16 + r15;
    const float bv = bias[n];
#pragma unroll
    for (int mi = 0; mi < 2; ++mi) {
      const int mbase = m0 + wm + mi * 16 + khalf * 4;
#pragma unroll
      for (int j = 0; j < 4; ++j) {
        const float t = fmaxf(acc[mi][ni][j] + bv, 0.f);
        const ushort h = bf16hi(t);
        const ushort l = bf16hi(t - bf16tof(h));
        outp[(size_t)(mbase + j) * 512 + n] = (unsigned)h | ((unsigned)l << 16);
      }
    }
  }
}

// ---------------- fused GEMM2 + residual + LN + gate/dsc, 64-row tile ------
__global__ __launch_bounds__(512, 2) void gemm2i_k(
    const unsigned* __restrict__ Ap, const char* __restrict__ w2ti,
    const float* __restrict__ b2, const int* __restrict__ seq,
    const float* __restrict__ embed, const float* __restrict__ gamma,
    const float* __restrict__ beta, const float* __restrict__ Wg,
    const float* __restrict__ bg, const float* __restrict__ Wd,
    const float* __restrict__ bd, float* __restrict__ X,
    int* __restrict__ wbit, float* __restrict__ dsc) {
  __shared__ alignas(16) unsigned Apk[2048];  // 64 rows x 8 chunks(4 u32)
  __shared__ alignas(16) ushort B[16384];     // 256 rows x 8 chunks
  __shared__ float par0[64][4], par1[64][4], gpar[64][4], dpar[64][4];
  __shared__ float g_s[256], be_s[256], wg_s[256], wd_s[256], b2_s[256];
  __shared__ int sidx[64];
  const int tid = threadIdx.x;
  const int m0 = blockIdx.x * 64;
  if (tid < 64) sidx[tid] = seq[m0 + tid];
  if (tid >= 256) {
    const int c = tid - 256;
    g_s[c] = gamma[c];
    be_s[c] = beta[c];
    wg_s[c] = Wg[c];
    wd_s[c] = Wd[c];
    b2_s[c] = b2[c];
  }
  const int lane = tid & 63, w = tid >> 6;
  const int wm = (w >> 2) * 32, wn = (w & 3) * 64;
  const int r15 = lane & 15, khalf = lane >> 4;

  f32x4 acc[2][4];
#pragma unroll
  for (int i = 0; i < 2; ++i)
#pragma unroll
    for (int j = 0; j < 4; ++j) acc[i][j] = (f32x4){0.f, 0.f, 0.f, 0.f};

#pragma unroll 1
  for (int s = 0; s < 16; ++s) {
    {  // A packed: 512 chunks, 1/thread
      const int cb = w * 64;
      const int c = cb + lane;
      const int row = c >> 3;
      const int lc = (c & 7) ^ (row & 7);
      gload_lds16(Ap + (size_t)(m0 + row) * 512 + s * 32 + lc * 4,
                  &Apk[cb * 4]);
    }
    const size_t sb = (size_t)s * 128;
#pragma unroll
    for (int i = 0; i < 4; ++i) {  // B: 2048 chunks
      const int cb = i * 512 + w * 64;
      const int c = cb + lane;
      const int row = c >> 3;
      const int lc = (c & 7) ^ (row & 7);
      gload_lds16(w2ti + (size_t)row * 2048 + sb + lc * 16, &B[cb * 8]);
    }
    __syncthreads();
    short8v ahf[2], alf[2], bhf[4], blf[4];
#pragma unroll
    for (int t = 0; t < 2; ++t) {
      const int ra = wm + t * 16 + r15;
      const int r7 = ra & 7;
      const uint4 ua = *(const uint4*)&Apk[(ra * 8 + ((khalf * 2) ^ r7)) * 4];
      const uint4 ub =
          *(const uint4*)&Apk[(ra * 8 + ((khalf * 2 + 1) ^ r7)) * 4];
      U8 vh, vl;
      vh.u[0] = (ua.x & 0xffffu) | (ua.y << 16);
      vl.u[0] = (ua.x >> 16) | (ua.y & 0xffff0000u);
      vh.u[1] = (ua.z & 0xffffu) | (ua.w << 16);
      vl.u[1] = (ua.z >> 16) | (ua.w & 0xffff0000u);
      vh.u[2] = (ub.x & 0xffffu) | (ub.y << 16);
      vl.u[2] = (ub.x >> 16) | (ub.y & 0xffff0000u);
      vh.u[3] = (ub.z & 0xffffu) | (ub.w << 16);
      vl.u[3] = (ub.z >> 16) | (ub.w & 0xffff0000u);
      ahf[t] = vh.v;
      alf[t] = vl.v;
    }
#pragma unroll
    for (int t = 0; t < 4; ++t) {
      const int rb = wn + t * 16 + r15;
      bhf[t] = *(const short8v*)&B[(rb * 8 + (khalf ^ (rb & 7))) * 8];
      blf[t] = *(const short8v*)&B[(rb * 8 + ((4 | khalf) ^ (rb & 7))) * 8];
    }
#pragma unroll
    for (int mi = 0; mi < 2; ++mi)
#pragma unroll
      for (int ni = 0; ni < 4; ++ni) {
        acc[mi][ni] = __builtin_amdgcn_mfma_f32_16x16x32_bf16(
            ahf[mi], bhf[ni], acc[mi][ni], 0, 0, 0);
        acc[mi][ni] = __builtin_amdgcn_mfma_f32_16x16x32_bf16(
            ahf[mi], blf[ni], acc[mi][ni], 0, 0, 0);
        acc[mi][ni] = __builtin_amdgcn_mfma_f32_16x16x32_bf16(
            alf[mi], bhf[ni], acc[mi][ni], 0, 0, 0);
      }
    __syncthreads();
  }

  // ---- epilogue: x = (acc + b2) + resid; then LN + gate/dsc ----
  float mu_r[2][4];
#pragma unroll
  for (int mi = 0; mi < 2; ++mi)
#pragma unroll
    for (int j = 0; j < 4; ++j) {
      const int rowl = wm + mi * 16 + khalf * 4 + j;
      const float* ep = embed + (size_t)sidx[rowl] * 256;
#pragma unroll
      for (int ni = 0; ni < 4; ++ni) {
        const int col = wn + ni * 16 + r15;
        float t = acc[mi][ni][j] + b2_s[col];
        acc[mi][ni][j] = t + ep[col];
      }
      float s = (acc[mi][0][j] + acc[mi][1][j]) + (acc[mi][2][j] + acc[mi][3][j]);
      s = dpp_sum16(s);
      if (r15 == 0) par0[rowl][w & 3] = s;
    }
  __syncthreads();
#pragma unroll
  for (int mi = 0; mi < 2; ++mi)
#pragma unroll
    for (int j = 0; j < 4; ++j) {
      const int rowl = wm + mi * 16 + khalf * 4 + j;
      const float mu = ((par0[rowl][0] + par0[rowl][1]) +
                        (par0[rowl][2] + par0[rowl][3])) * (1.f / 256.f);
      mu_r[mi][j] = mu;
      const float d0 = acc[mi][0][j] - mu, d1 = acc[mi][1][j] - mu;
      const float d2 = acc[mi][2][j] - mu, d3 = acc[mi][3][j] - mu;
      float vv = (d0 * d0 + d1 * d1) + (d2 * d2 + d3 * d3);
      vv = dpp_sum16(vv);
      if (r15 == 0) par1[rowl][w & 3] = vv;
    }
  __syncthreads();
#pragma unroll
  for (int mi = 0; mi < 2; ++mi)
#pragma unroll
    for (int j = 0; j < 4; ++j) {
      const int rowl = wm + mi * 16 + khalf * 4 + j;
      const float mu = mu_r[mi][j];
      const float var = ((par1[rowl][0] + par1[rowl][1]) +
                         (par1[rowl][2] + par1[rowl][3])) * (1.f / 256.f);
      const float rstd = 1.f / sqrtf(var + 1e-5f);
      float ys[4], gw[4], dw[4];
#pragma unroll
      for (int ni = 0; ni < 4; ++ni) {
        const int col = wn + ni * 16 + r15;
        const float y = (acc[mi][ni][j] - mu) * rstd * g_s[col] + be_s[col];
        X[(size_t)(m0 + rowl) * 256 + col] = y;
        ys[ni] = y;
        gw[ni] = wg_s[col];
        dw[ni] = wd_s[col];
      }
      float gp = (ys[0] * gw[0] + ys[1] * gw[1]) + (ys[2] * gw[2] + ys[3] * gw[3]);
      float dp = (ys[0] * dw[0] + ys[1] * dw[1]) + (ys[2] * dw[2] + ys[3] * dw[3]);
      gp = dpp_sum16(gp);
      dp = dpp_sum16(dp);
      if (r15 == 0) {
        gpar[rowl][w & 3] = gp;
        dpar[rowl][w & 3] = dp;
      }
    }
  __syncthreads();
  if (tid < 64) {
    const int row = tid;
    const float gs = ((gpar[row][0] + gpar[row][1]) +
                      (gpar[row][2] + gpar[row][3])) + bg[0];
    const float dsv = ((dpar[row][0] + dpar[row][1]) +
                       (dpar[row][2] + dpar[row][3])) + bd[0];
    float sig;
    if (gs >= 0.f) {
      sig = 1.f / (1.f + expf(-gs));
    } else {
      const float e2 = expf(gs);
      sig = e2 / (1.f + e2);
    }
    wbit[m0 + row] = (sig >= 0.4f) ? 1 : 0;
    dsc[m0 + row] = dsv;
  }
}

// ---------------- strip-parallel rank kernel: grid (8 strips, 32 batches) --
__global__ __launch_bounds__(1024) void rank_k(
    const int* __restrict__ wbit, const float* __restrict__ dsc,
    unsigned* __restrict__ r12) {
  const int b = blockIdx.y;
  const int s0 = blockIdx.x * 128;
  const int tid = threadIdx.x;
  const int lane = tid & 63, wv = tid >> 6;
  __shared__ unsigned long long skey[1024];
  __shared__ int wavecnt[16];
  __shared__ int waveoff[17];

  int flag = 0;
  float d = 0.f;
  if (tid < 1021) {
    flag = wbit[b * 1024 + tid];
    d = dsc[b * 1024 + tid];
  }
  const unsigned long long m = __ballot(flag != 0);
  if (lane == 0) wavecnt[wv] = __popcll(m);
  skey[tid] = ~0ull;
  __syncthreads();
  if (tid == 0) {
    int acc = 0;
    for (int i = 0; i < 16; ++i) { waveoff[i] = acc; acc += wavecnt[i]; }
    waveoff[16] = acc;
  }
  __syncthreads();
  const int W = waveoff[16];
  if (flag) {
    unsigned u = __float_as_uint(d);
    u = (u & 0x80000000u) ? ~u : (u | 0x80000000u);
    const int w = waveoff[wv] + __popcll(m & ((1ull << lane) - 1ull));
    skey[w] = ((unsigned long long)u << 32) | (unsigned)w;
  }
  __syncthreads();
  const unsigned long long ki = skey[tid];  // own key (MAX if tid >= W)
  __syncthreads();
  if (tid == W - 1) skey[tid] = ~0ull;  // exclude last write from ranks
  __syncthreads();

  const int end2 = max(0, W - 257);
  int r1 = 0, r2 = 0;
#pragma unroll 8
  for (int jj = 0; jj < 128; ++jj) {
    const int j = s0 + jj;
    const int lt = skey[j] < ki;
    r1 += lt;
    r2 += (j < end2) ? lt : 0;
  }
  r12[((size_t)b * 8 + blockIdx.x) * 1024 + tid] =
      (unsigned)r1 | ((unsigned)r2 << 16);
}

// ---------------- fused select + attention (ranks from rank_k partials) ----
__global__ __launch_bounds__(1024) void selattn_k(
    const int* __restrict__ wbit, const float* __restrict__ dsc,
    const unsigned* __restrict__ r12, const float* __restrict__ X,
    const float* __restrict__ Wq, const float* __restrict__ bq,
    float* __restrict__ ctx, float* __restrict__ needs_out) {
  const int b = blockIdx.x;
  const int tid = threadIdx.x;
  const int lane = tid & 63, wv = tid >> 6;
  __shared__ int stokl[1024];
  __shared__ int wavecnt[16];
  __shared__ int waveoff[17];
  __shared__ int fcnt_s[16], scnt_s[16];
  __shared__ int foff[16], soff[16];
  __shared__ int ft[64], st[256];
  __shared__ float hl[256], q[256];
  __shared__ float qpart[4][256];
  __shared__ float sc_f[64], at_f[64];
  __shared__ float sc_s[256], at_s[256];
  __shared__ float redm[4], reds[4];
  __shared__ float needs_s;
  __shared__ float cpart[16][256];

  int flag = 0;
  if (tid < 1021) flag = wbit[b * 1024 + tid];
  const unsigned long long m = __ballot(flag != 0);
  if (lane == 0) wavecnt[wv] = __popcll(m);
  __syncthreads();
  if (tid == 0) {
    int acc = 0;
    for (int i = 0; i < 16; ++i) { waveoff[i] = acc; acc += wavecnt[i]; }
    waveoff[16] = acc;
  }
  __syncthreads();
  const int W = waveoff[16];
  if (flag) {
    const int w = waveoff[wv] + __popcll(m & ((1ull << lane) - 1ull));
    stokl[w] = tid;
  }
  __syncthreads();

  int r1 = 0, r2 = 0;
  {
    const unsigned* rp = r12 + (size_t)b * 8192 + tid;
#pragma unroll
    for (int s = 0; s < 8; ++s) {
      const unsigned v = rp[s * 1024];
      r1 += (int)(v & 0xffffu);
      r2 += (int)(v >> 16);
    }
  }
  const int K = W - 64;
  const int end2 = max(0, W - 257);
  bool fastf = false, slowf = false;
  if (tid < W) {
    const bool isLast = (tid == W - 1);
    const bool inEK = (!isLast) && (r1 < K);
    const bool inE2 = (tid < end2) && (r2 < K - 256);
    fastf = isLast || (!isLast && r1 >= K);
    slowf = inEK && !inE2;
  }

  const unsigned long long mf = __ballot(fastf);
  const unsigned long long ms = __ballot(slowf);
  if (lane == 0) { fcnt_s[wv] = __popcll(mf); scnt_s[wv] = __popcll(ms); }
  __syncthreads();
  if (tid == 0) {
    int a = 0, c = 0;
    for (int i = 0; i < 16; ++i) {
      foff[i] = a; a += fcnt_s[i];
      soff[i] = c; c += scnt_s[i];
    }
  }
  __syncthreads();
  if (fastf) {
    const int p = foff[wv] + __popcll(mf & ((1ull << lane) - 1ull));
    ft[p] = stokl[tid];
  }
  if (slowf) {
    const int p = soff[wv] + __popcll(ms & ((1ull << lane) - 1ull));
    st[p] = stokl[tid];
  }
  const int nf = min(W, 64);
  const int ns = min(max(K, 0), 256);

  // ---- phase 2: attention ----
  const float* Xb = X + (size_t)b * 1024 * 256;
  if (tid < 256) hl[tid] = Xb[(size_t)1023 * 256 + tid];
  __syncthreads();

  {
    const int col = tid & 255, kc = tid >> 8;
    float a = 0.f;
    const float* wp = Wq + (size_t)(kc * 64) * 256 + col;
#pragma unroll 4
    for (int k = 0; k < 64; ++k) a = fmaf(hl[kc * 64 + k], wp[(size_t)k * 256], a);
    qpart[kc][col] = a;
  }
  __syncthreads();
  if (tid < 256)
    q[tid] = ((qpart[0][tid] + qpart[1][tid]) + qpart[2][tid]) + qpart[3][tid] +
             bq[tid];
  __syncthreads();

  const float4 qq = *(const float4*)(q + lane * 4);
#pragma unroll 2
  for (int i = 0; i < 20; ++i) {
    const int r = wv + 16 * i;
    bool valid;
    int tok;
    if (r < 64) { valid = r < nf; tok = valid ? ft[r] : 0; }
    else        { valid = (r - 64) < ns; tok = valid ? st[r - 64] : 0; }
    float sc = NEGV;
    if (valid) {
      const float4 xr = *(const float4*)(Xb + (size_t)tok * 256 + lane * 4);
      float p = (xr.x * qq.x + xr.y * qq.y) + (xr.z * qq.z + xr.w * qq.w);
      sc = dpp_sum63(p);
    }
    if (lane == 63) {
      if (r < 64) sc_f[r] = sc;
      else sc_s[r - 64] = sc;
    }
  }
  __syncthreads();

  if (wv < 4) {
    float s = sc_s[tid];
    float mx = wred_max(s);
    if (lane == 0) redm[wv] = mx;
  } else if (wv == 8) {
    float s = sc_f[lane];
    float mx = wred_max(s);
    float e = expf(s - mx);
    float sm = wred_sum(e);
    float a = e / sm;
    at_f[lane] = a;
    float ma = wred_max(a);
    if (lane == 0) needs_s = (ma < 0.3f) ? 1.f : 0.f;
  }
  __syncthreads();
  if (wv < 4) {
    float s = sc_s[tid];
    float mx = fmaxf(fmaxf(redm[0], redm[1]), fmaxf(redm[2], redm[3]));
    float e = expf(s - mx);
    float sm = wred_sum(e);
    if (lane == 0) reds[wv] = sm;
    at_s[tid] = e;
  }
  __syncthreads();
  if (tid < 256) {
    float sm = (reds[0] + reds[1]) + (reds[2] + reds[3]);
    at_s[tid] = at_s[tid] / sm;
  }
  __syncthreads();

  const float needs = needs_s;
  float4 cp = {0.f, 0.f, 0.f, 0.f};
#pragma unroll 2
  for (int i = 0; i < 20; ++i) {
    const int r = wv + 16 * i;
    bool valid;
    int tok;
    float a;
    if (r < 64) { valid = r < nf; tok = valid ? ft[r] : 0; a = at_f[r]; }
    else {
      valid = (r - 64) < ns;
      tok = valid ? st[r - 64] : 0;
      a = needs * at_s[r - 64];
    }
    if (valid) {
      const float4 xr = *(const float4*)(Xb + (size_t)tok * 256 + lane * 4);
      cp.x = fmaf(a, xr.x, cp.x);
      cp.y = fmaf(a, xr.y, cp.y);
      cp.z = fmaf(a, xr.z, cp.z);
      cp.w = fmaf(a, xr.w, cp.w);
    }
  }
  *(float4*)&cpart[wv][lane * 4] = cp;
  __syncthreads();
  if (tid < 256) {
    float c = 0.f;
#pragma unroll
    for (int w = 0; w < 16; ++w) c += cpart[w][tid];
    ctx[b * 256 + tid] = c;
  }
  if (tid == 0) needs_out[b] = needs;
}

// ---------------- logits: grid (125,4), 8 batches, float4 LDS reads --------
__global__ __launch_bounds__(256) void logits5_k(
    const float* __restrict__ ctx, const float* __restrict__ Wo,
    const float* __restrict__ bo, float* __restrict__ out) {
  __shared__ float cs[256 * 8];  // [h][bb]
  const int tid = threadIdx.x;
  const int b0 = blockIdx.y * 8;
  for (int i = tid; i < 2048; i += 256) {
    int bb = i & 7, hh = i >> 3;
    cs[hh * 8 + bb] = ctx[(b0 + bb) * 256 + hh];
  }
  __syncthreads();
  const int v = blockIdx.x * 256 + tid;
  float acc[8] = {0.f, 0.f, 0.f, 0.f, 0.f, 0.f, 0.f, 0.f};
  for (int h0 = 0; h0 < 256; h0 += 16) {
    float wv[16];
#pragma unroll
    for (int u = 0; u < 16; ++u) wv[u] = Wo[(size_t)(h0 + u) * 32000 + v];
#pragma unroll
    for (int u = 0; u < 16; ++u) {
      const float4 c0 = *(const float4*)&cs[(h0 + u) * 8];
      const float4 c1 = *(const float4*)&cs[(h0 + u) * 8 + 4];
      acc[0] = fmaf(c0.x, wv[u], acc[0]);
      acc[1] = fmaf(c0.y, wv[u], acc[1]);
      acc[2] = fmaf(c0.z, wv[u], acc[2]);
      acc[3] = fmaf(c0.w, wv[u], acc[3]);
      acc[4] = fmaf(c1.x, wv[u], acc[4]);
      acc[5] = fmaf(c1.y, wv[u], acc[5]);
      acc[6] = fmaf(c1.z, wv[u], acc[6]);
      acc[7] = fmaf(c1.w, wv[u], acc[7]);
    }
  }
  const float bv = bo[v];
#pragma unroll
  for (int bb = 0; bb < 8; ++bb)
    out[(size_t)(b0 + bb) * 32000 + v] = acc[bb] + bv;
}

extern "C" void kernel_launch(void* const* d_in, const int* in_sizes, int n_in,
                              void* d_out, int out_size, void* d_ws,
                              size_t ws_size, hipStream_t stream) {
  const int* seq = (const int*)d_in[0];
  const float* embed = (const float*)d_in[1];
  const float* W1 = (const float*)d_in[2];
  const float* b1 = (const float*)d_in[3];
  const float* W2 = (const float*)d_in[4];
  const float* b2 = (const float*)d_in[5];
  const float* gamma = (const float*)d_in[6];
  const float* beta = (const float*)d_in[7];
  const float* Wg = (const float*)d_in[8];
  const float* bg = (const float*)d_in[9];
  const float* Wd = (const float*)d_in[10];
  const float* bd = (const float*)d_in[11];
  const float* Wq = (const float*)d_in[12];
  const float* bq = (const float*)d_in[13];
  const float* Wo = (const float*)d_in[14];
  const float* bo = (const float*)d_in[15];
  float* out = (float*)d_out;

  char* wsb = (char*)d_ws;
  char* w1ti = wsb;                        // 512*256*4 = 512 KiB
  char* w2ti = wsb + 524288;               // 256*512*4 = 512 KiB
  int* wbit = (int*)(wsb + 1048576);       // 32768*4
  float* dscp = (float*)(wsb + 1179648);
  float* ctxp = (float*)(wsb + 1310720);   // 32*256*4
  unsigned* r12p = (unsigned*)(wsb + 1343488);  // 32*8*1024*4 = 1 MiB
  const size_t base = 2392064;

  // full mode needs base + 64M (act1p) + 32M (X) ~= 99 MB
  const int nch = (ws_size >= (size_t)106000000) ? 1 : 2;
  const int rows = 32768 / nch;
  const size_t actsz = (size_t)rows * 512 * 4;
  unsigned* act1p = (unsigned*)(wsb + base);
  float* X = (float*)(wsb + base + actsz);

  dim3 blk(256);
  wprep2_k<<<dim3(8, 16), blk, 0, stream>>>(W1, w1ti, 256, 512);
  wprep2_k<<<dim3(16, 8), blk, 0, stream>>>(W2, w2ti, 512, 256);

  for (int c = 0; c < nch; ++c) {
    const int* seqc = seq + c * rows;
    gemm1g_k<<<dim3(rows / 64, 2), dim3(512), 0, stream>>>(seqc, embed, w1ti,
                                                           b1, act1p);
    gemm2i_k<<<dim3(rows / 64), dim3(512), 0, stream>>>(
        act1p, w2ti, b2, seqc, embed, gamma, beta, Wg, bg, Wd, bd,
        X + (size_t)c * rows * 256, wbit + c * rows, dscp + c * rows);
  }

  rank_k<<<dim3(8, 32), dim3(1024), 0, stream>>>(wbit, dscp, r12p);
  selattn_k<<<32, dim3(1024), 0, stream>>>(wbit, dscp, r12p, X, Wq, bq, ctxp,
                                           out + (size_t)32 * 32000);
  logits5_k<<<dim3(125, 4), blk, 0, stream>>>(ctxp, Wo, bo, out);
}